// Round 6
// baseline (922.178 us; speedup 1.0000x reference)
//
#include <hip/hip_runtime.h>
#include <math.h>

#define NEGBIG (-1e30f)

typedef __bf16 bf16x8 __attribute__((ext_vector_type(8)));
typedef float  f32x4  __attribute__((ext_vector_type(4)));

// Sizes: B=512, S=8, U=512, D=32, G=8, DIM_IN=4096, DAG=2048
// out layout: att[512*16384] | ga[512*2048] | w[512^3] | outputs[512*16384]
// outs region doubles as stats scratch between K3a and K3b: cell (b,u) floats
// [0..7]=M per group, [8..15]=1/(8L). Written by one K3a block, read then fully
// overwritten by exactly one K3b block -> no hazard, fully rewritten every call.

// ---------------- K1/K2: per-split fp32 GEMM (64x64 tile, Kstep 16) ----------------
__global__ __launch_bounds__(256) void gemm_split(
    const float* __restrict__ A, int lda, int Ksz,
    const float* __restrict__ Bw, int NS,
    const float* __restrict__ bias,
    float* __restrict__ C, int ldc)
{
  const int n0 = blockIdx.x * 64;
  const int b0 = blockIdx.y * 64;
  const int s  = n0 / NS;
  const float* Bp = Bw + (size_t)s * Ksz * NS;
  const int nloc0 = n0 - s * NS;
  const int acol0 = s * Ksz;

  __shared__ float As[16][64];
  __shared__ float Bs[16][64];

  const int t  = threadIdx.x;
  const int tb = t & 15, tn = t >> 4;
  float acc[4][4] = {};

  for (int k0 = 0; k0 < Ksz; k0 += 16) {
    {
      int r = t & 63, g = t >> 6;
      float4 v = *reinterpret_cast<const float4*>(
          A + (size_t)(b0 + r) * lda + acol0 + k0 + 4 * g);
      As[4*g+0][r] = v.x; As[4*g+1][r] = v.y; As[4*g+2][r] = v.z; As[4*g+3][r] = v.w;
    }
    {
      int kk = t >> 4, n4 = t & 15;
      float4 v = *reinterpret_cast<const float4*>(
          Bp + (size_t)(k0 + kk) * NS + nloc0 + 4 * n4);
      *reinterpret_cast<float4*>(&Bs[kk][4*n4]) = v;
    }
    __syncthreads();
#pragma unroll
    for (int k = 0; k < 16; ++k) {
      float4 a4 = *reinterpret_cast<const float4*>(&As[k][4*tb]);
      float4 b4 = *reinterpret_cast<const float4*>(&Bs[k][4*tn]);
      float av[4] = {a4.x, a4.y, a4.z, a4.w};
      float bv[4] = {b4.x, b4.y, b4.z, b4.w};
#pragma unroll
      for (int i = 0; i < 4; ++i)
#pragma unroll
        for (int j = 0; j < 4; ++j)
          acc[i][j] = fmaf(av[i], bv[j], acc[i][j]);
    }
    __syncthreads();
  }
#pragma unroll
  for (int i = 0; i < 4; ++i) {
    int row = b0 + 4*tb + i;
    int col = n0 + 4*tn;
    float4 o;
    o.x = acc[i][0] + bias[col + 0];
    o.y = acc[i][1] + bias[col + 1];
    o.z = acc[i][2] + bias[col + 2];
    o.w = acc[i][3] + bias[col + 3];
    *reinterpret_cast<float4*>(C + (size_t)row * ldc + col) = o;
  }
}

// ---------------- K3a (MFMA): masked raw scores + online group stats ----------------
// Block 16b x 16u, 4 waves; wave w owns u-locals {4w..4w+3}. Per 16-m chunk:
//   MFMA role: B-frag (ma) direct from global, split-bf16 (hi+lo), 3 MFMAs per u;
//              raw C -> LDS tr[bm][17] (scalar writes ~4-way, reads 2-way).
//   Emit role: thread t=(bl,ml) owns (b,m) for 16 u: coalesced rnd f4 reads (dbuf),
//              *temp, mask, coalesced w f4 writes, online M/L in 32 regs (g=ml&7).
// Epilogue: shfl_xor(8) merge (ml vs ml+8 own the same group), ml<8 writes stats.
__global__ __launch_bounds__(256) void scores_stats_mfma(
    const float* __restrict__ att,   // [512][512][32]
    const float* __restrict__ ma,    // [512][512][32]
    const float* __restrict__ rnd,   // [512][512][512]
    const float* __restrict__ temp,  // [512]
    float* __restrict__ wout,        // [512][512][512] raw masked scores
    float* __restrict__ stats)       // outs region base
{
  __shared__ float tr[256 * 17];     // 17 KB
  const int b0 = blockIdx.x * 16;
  const int u0 = blockIdx.y * 16;
  const int t  = threadIdx.x;
  const int w  = t >> 6, l = t & 63;
  const int lo16 = l & 15, kb = l >> 4;    // MFMA role: A-row / B-col, k-block
  const int bl = t >> 4, ml = t & 15;      // emit role: (b,m) owner
  const int gb = b0 + bl;

  // temperature for the 16 u's
  float tvf[16];
#pragma unroll
  for (int q = 0; q < 4; ++q) {
    float4 tq = *reinterpret_cast<const float4*>(temp + u0 + 4 * q);
    tvf[4*q+0] = tq.x; tvf[4*q+1] = tq.y; tvf[4*q+2] = tq.z; tvf[4*q+3] = tq.w;
  }

  // A-fragments (att) for this wave's 4 u's, split hi/lo bf16
  bf16x8 Ahi[4], Alo[4];
#pragma unroll
  for (int q = 0; q < 4; ++q) {
    const float* ap = att + (size_t)(b0 + lo16) * 16384
                    + (size_t)(u0 + 4 * w + q) * 32 + kb * 8;
    float4 a0 = *reinterpret_cast<const float4*>(ap);
    float4 a1 = *reinterpret_cast<const float4*>(ap + 4);
    float af[8] = {a0.x, a0.y, a0.z, a0.w, a1.x, a1.y, a1.z, a1.w};
#pragma unroll
    for (int j = 0; j < 8; ++j) {
      __bf16 h = (__bf16)af[j];
      Ahi[q][j] = h;
      Alo[q][j] = (__bf16)(af[j] - (float)h);
    }
  }

  float M[16], L[16];
#pragma unroll
  for (int u = 0; u < 16; ++u) { M[u] = NEGBIG; L[u] = 0.f; }

  const float* rb = rnd  + (size_t)gb * 262144 + u0;   // + m*512
  float*       wb = wout + (size_t)gb * 262144 + u0;

  // rnd double-buffer: chunk 0
  float4 rv[4], rnx[4];
#pragma unroll
  for (int q = 0; q < 4; ++q)
    rv[q] = *reinterpret_cast<const float4*>(rb + (size_t)ml * 512 + 4 * q);

#pragma unroll 1
  for (int c = 0; c < 32; ++c) {
    const int m0 = c * 16;

    // ---- MFMA role: scores for 4 u's of this wave ----
#pragma unroll
    for (int q = 0; q < 4; ++q) {
      const float* bp = ma + (size_t)(m0 + lo16) * 16384
                      + (size_t)(u0 + 4 * w + q) * 32 + kb * 8;
      float4 b0v = *reinterpret_cast<const float4*>(bp);
      float4 b1v = *reinterpret_cast<const float4*>(bp + 4);
      float bf[8] = {b0v.x, b0v.y, b0v.z, b0v.w, b1v.x, b1v.y, b1v.z, b1v.w};
      bf16x8 Bhi, Blo;
#pragma unroll
      for (int j = 0; j < 8; ++j) {
        __bf16 h = (__bf16)bf[j];
        Bhi[j] = h;
        Blo[j] = (__bf16)(bf[j] - (float)h);
      }
      f32x4 acc = {0.f, 0.f, 0.f, 0.f};
      acc = __builtin_amdgcn_mfma_f32_16x16x32_bf16(Ahi[q], Blo, acc, 0, 0, 0);
      acc = __builtin_amdgcn_mfma_f32_16x16x32_bf16(Alo[q], Bhi, acc, 0, 0, 0);
      acc = __builtin_amdgcn_mfma_f32_16x16x32_bf16(Ahi[q], Bhi, acc, 0, 0, 0);
      // C layout: col=lane&15 (m), row=(lane>>4)*4+i (b)
#pragma unroll
      for (int i = 0; i < 4; ++i)
        tr[((kb * 4 + i) * 16 + lo16) * 17 + 4 * w + q] = acc[i];
    }
    __syncthreads();                   // tr complete

    // prefetch rnd for next chunk (flies across this chunk's emit work)
    if (c < 31) {
#pragma unroll
      for (int q = 0; q < 4; ++q)
        rnx[q] = *reinterpret_cast<const float4*>(
            rb + (size_t)(m0 + 16 + ml) * 512 + 4 * q);
    }

    // ---- emit role: (b=gb, m=m0+ml), 16 u ----
    const int gm = m0 + ml;
    const bool dg = (gm == gb);
    float sv[16];
#pragma unroll
    for (int q = 0; q < 4; ++q) {
      float rr[4] = {rv[q].x, rv[q].y, rv[q].z, rv[q].w};
#pragma unroll
      for (int e = 0; e < 4; ++e) {
        const int u = 4 * q + e;
        float s = tr[t * 17 + u] * tvf[u];
        if ((rr[e] < 0.1f) | dg) s = NEGBIG;
        sv[u] = s;
        float d = s - M[u];
        if (d > 0.f) { L[u] = fmaf(L[u], __expf(-d), 1.f); M[u] = s; }
        else          L[u] += __expf(d);
      }
    }
    {
      float* wp = wb + (size_t)gm * 512;
#pragma unroll
      for (int q = 0; q < 4; ++q)
        *reinterpret_cast<float4*>(wp + 4 * q) =
            make_float4(sv[4*q], sv[4*q+1], sv[4*q+2], sv[4*q+3]);
    }
    __syncthreads();                   // tr consumed before next chunk's writes
#pragma unroll
    for (int q = 0; q < 4; ++q) rv[q] = rnx[q];
  }

  // ---- stats epilogue: merge (ml, ml^8) partials, write cells ----
#pragma unroll
  for (int u = 0; u < 16; ++u) {
    float oM = __shfl_xor(M[u], 8, 64);
    float oL = __shfl_xor(L[u], 8, 64);
    float nm = fmaxf(M[u], oM);
    float Lm = L[u] * __expf(M[u] - nm) + oL * __expf(oM - nm);
    if ((t & 8) == 0) {
      float* cell = stats + ((size_t)gb * 512 + u0 + u) * 32;
      cell[t & 7]       = nm;
      cell[8 + (t & 7)] = 1.0f / (8.0f * Lm);
    }
  }
}

// ---------------- K3b v2: w = exp(s-M)/(8L) + outputs, 16b x 16u blocks ----------
__global__ __launch_bounds__(256) void emit_outputs_v2(
    const float* __restrict__ mo,    // [512][512][32]
    float* __restrict__ w,           // in: raw scores, out: final w
    float* __restrict__ outs)        // in: stats cells, out: outputs [512][512][32]
{
  __shared__ float MoL[8 * 16 * 32];
  __shared__ float E[8 * 16 * 17];
  const int u0 = blockIdx.x * 16;
  const int b0 = blockIdx.y * 16;
  const int t  = threadIdx.x;
  const int ab = t >> 4, am = (t >> 1) & 7, uh = t & 1;
  const int pu = t >> 4, bq = (t >> 2) & 3, dh = t & 3;

  float Mreg[8], Sreg[8];
  {
    const float* cb = outs + ((size_t)(b0 + ab) * 512 + u0 + uh * 8) * 32;
#pragma unroll
    for (int j = 0; j < 8; ++j) {
      Mreg[j] = cb[j * 32 + am];
      Sreg[j] = cb[j * 32 + 8 + am];
    }
  }

  float4 acc[4][2];
#pragma unroll
  for (int i = 0; i < 4; ++i) {
    acc[i][0] = make_float4(0.f, 0.f, 0.f, 0.f);
    acc[i][1] = make_float4(0.f, 0.f, 0.f, 0.f);
  }

  float* wbase = w + (size_t)(b0 + ab) * 262144 + u0 + uh * 8;   // + m*512

  const float* msrc0;  const float* msrc1;  const float* msrc2;  const float* msrc3;
  int loff0, loff1, loff2, loff3;
  {
    int P, mm, uu, dq;
    P = t;          mm = P >> 7; uu = (P >> 3) & 15; dq = P & 7;
    msrc0 = mo + (size_t)mm * 16384 + (size_t)(u0 + uu) * 32 + (dq ^ (uu & 7)) * 4;
    loff0 = P * 4;
    P = 256 + t;    mm = P >> 7; uu = (P >> 3) & 15; dq = P & 7;
    msrc1 = mo + (size_t)mm * 16384 + (size_t)(u0 + uu) * 32 + (dq ^ (uu & 7)) * 4;
    loff1 = P * 4;
    P = 512 + t;    mm = P >> 7; uu = (P >> 3) & 15; dq = P & 7;
    msrc2 = mo + (size_t)mm * 16384 + (size_t)(u0 + uu) * 32 + (dq ^ (uu & 7)) * 4;
    loff2 = P * 4;
    P = 768 + t;    mm = P >> 7; uu = (P >> 3) & 15; dq = P & 7;
    msrc3 = mo + (size_t)mm * 16384 + (size_t)(u0 + uu) * 32 + (dq ^ (uu & 7)) * 4;
    loff3 = P * 4;
  }

  float4 wpre0, wpre1, smo0, smo1, smo2, smo3;
  {
    const float* wp = wbase + (size_t)am * 512;
    wpre0 = *reinterpret_cast<const float4*>(wp);
    wpre1 = *reinterpret_cast<const float4*>(wp + 4);
    smo0 = *reinterpret_cast<const float4*>(msrc0);
    smo1 = *reinterpret_cast<const float4*>(msrc1);
    smo2 = *reinterpret_cast<const float4*>(msrc2);
    smo3 = *reinterpret_cast<const float4*>(msrc3);
  }

#pragma unroll 1
  for (int c = 0; c < 64; ++c) {
    const int mc = c * 8;
    if (c) __syncthreads();

    {
      float* wp = wbase + (size_t)(mc + am) * 512;
      float s0[4] = {wpre0.x, wpre0.y, wpre0.z, wpre0.w};
      float s1[4] = {wpre1.x, wpre1.y, wpre1.z, wpre1.w};
#pragma unroll
      for (int e2 = 0; e2 < 4; ++e2) {
        float v = __expf(s0[e2] - Mreg[e2]) * Sreg[e2];
        s0[e2] = v;
        E[(am * 16 + uh * 8 + e2) * 17 + ab] = v;
      }
#pragma unroll
      for (int e2 = 0; e2 < 4; ++e2) {
        float v = __expf(s1[e2] - Mreg[4 + e2]) * Sreg[4 + e2];
        s1[e2] = v;
        E[(am * 16 + uh * 8 + 4 + e2) * 17 + ab] = v;
      }
      *reinterpret_cast<float4*>(wp)     = make_float4(s0[0], s0[1], s0[2], s0[3]);
      *reinterpret_cast<float4*>(wp + 4) = make_float4(s1[0], s1[1], s1[2], s1[3]);
    }
    *reinterpret_cast<float4*>(&MoL[loff0]) = smo0;
    *reinterpret_cast<float4*>(&MoL[loff1]) = smo1;
    *reinterpret_cast<float4*>(&MoL[loff2]) = smo2;
    *reinterpret_cast<float4*>(&MoL[loff3]) = smo3;
    __syncthreads();

    if (c < 63) {
      const float* wp = wbase + (size_t)(mc + 8 + am) * 512;
      wpre0 = *reinterpret_cast<const float4*>(wp);
      wpre1 = *reinterpret_cast<const float4*>(wp + 4);
      const size_t moff = (size_t)(mc + 8) * 16384;
      smo0 = *reinterpret_cast<const float4*>(msrc0 + moff);
      smo1 = *reinterpret_cast<const float4*>(msrc1 + moff);
      smo2 = *reinterpret_cast<const float4*>(msrc2 + moff);
      smo3 = *reinterpret_cast<const float4*>(msrc3 + moff);
    }

#pragma unroll
    for (int m = 0; m < 8; ++m) {
      float4 ef = *reinterpret_cast<const float4*>(&E[(m * 16 + pu) * 17 + 4 * bq]);
      float4 v0 = *reinterpret_cast<const float4*>(
          &MoL[(m * 16 + pu) * 32 + (((2 * dh) ^ (pu & 7)) * 4)]);
      float4 v1 = *reinterpret_cast<const float4*>(
          &MoL[(m * 16 + pu) * 32 + (((2 * dh + 1) ^ (pu & 7)) * 4)]);
      float es[4] = {ef.x, ef.y, ef.z, ef.w};
#pragma unroll
      for (int i = 0; i < 4; ++i) {
        acc[i][0].x = fmaf(es[i], v0.x, acc[i][0].x);
        acc[i][0].y = fmaf(es[i], v0.y, acc[i][0].y);
        acc[i][0].z = fmaf(es[i], v0.z, acc[i][0].z);
        acc[i][0].w = fmaf(es[i], v0.w, acc[i][0].w);
        acc[i][1].x = fmaf(es[i], v1.x, acc[i][1].x);
        acc[i][1].y = fmaf(es[i], v1.y, acc[i][1].y);
        acc[i][1].z = fmaf(es[i], v1.z, acc[i][1].z);
        acc[i][1].w = fmaf(es[i], v1.w, acc[i][1].w);
      }
    }
  }

#pragma unroll
  for (int i = 0; i < 4; ++i) {
    float* dst = outs + ((size_t)(b0 + 4 * bq + i) * 512 + u0 + pu) * 32 + 8 * dh;
    *reinterpret_cast<float4*>(dst)     = acc[i][0];
    *reinterpret_cast<float4*>(dst + 4) = acc[i][1];
  }
}

extern "C" void kernel_launch(void* const* d_in, const int* in_sizes, int n_in,
                              void* d_out, int out_size, void* d_ws, size_t ws_size,
                              hipStream_t stream) {
  const float* x    = (const float*)d_in[0];   // [512][4096]
  const float* ma   = (const float*)d_in[1];   // [512][512][32]
  const float* mo   = (const float*)d_in[2];   // [512][512][32]
  const float* rnd  = (const float*)d_in[3];   // [512][512][512]
  const float* w1   = (const float*)d_in[4];   // [8][512][256]
  const float* b1   = (const float*)d_in[5];   // [8][256]
  const float* w2   = (const float*)d_in[6];   // [8][256][2048]
  const float* b2   = (const float*)d_in[7];   // [8][2048]
  const float* temp = (const float*)d_in[8];   // [512]

  float* out  = (float*)d_out;
  float* att  = out;                  // 8388608
  float* ga   = out + 8388608;        // 1048576
  float* wbuf = out + 9437184;        // 134217728
  float* outs = out + 143654912;      // 8388608

  gemm_split<<<dim3(32, 8), 256, 0, stream>>>(x, 4096, 512, w1, 256, b1, ga, 2048);
  gemm_split<<<dim3(256, 8), 256, 0, stream>>>(ga, 2048, 256, w2, 2048, b2, att, 16384);
  scores_stats_mfma<<<dim3(32, 32), 256, 0, stream>>>(att, ma, rnd, temp, wbuf, outs);
  emit_outputs_v2<<<dim3(32, 32), 256, 0, stream>>>(mo, wbuf, outs);
}

// Round 7
// 900.183 us; speedup vs baseline: 1.0244x; 1.0244x over previous
//
#include <hip/hip_runtime.h>
#include <math.h>

#define NEGBIG (-1e30f)

// Sizes: B=512, S=8, U=512, D=32, G=8, DIM_IN=4096, DAG=2048
// out layout: att[512*16384] | ga[512*2048] | w[512^3] | outputs[512*16384]
// No-max softmax: pass 1 stores p = exp(s) (masked -> 0) into the w region and
// accumulates L_g = sum p; stats cell (b,u) floats [0..7] = 1/(8 L_g).
// Pass 2: w = p * IL_g + PV accumulation. Stats cells are overwritten by outputs.

// ---------------- K1/K2: per-split fp32 GEMM (64x64 tile, Kstep 16) ----------------
__global__ __launch_bounds__(256) void gemm_split(
    const float* __restrict__ A, int lda, int Ksz,
    const float* __restrict__ Bw, int NS,
    const float* __restrict__ bias,
    float* __restrict__ C, int ldc)
{
  const int n0 = blockIdx.x * 64;
  const int b0 = blockIdx.y * 64;
  const int s  = n0 / NS;
  const float* Bp = Bw + (size_t)s * Ksz * NS;
  const int nloc0 = n0 - s * NS;
  const int acol0 = s * Ksz;

  __shared__ float As[16][64];
  __shared__ float Bs[16][64];

  const int t  = threadIdx.x;
  const int tb = t & 15, tn = t >> 4;
  float acc[4][4] = {};

  for (int k0 = 0; k0 < Ksz; k0 += 16) {
    {
      int r = t & 63, g = t >> 6;
      float4 v = *reinterpret_cast<const float4*>(
          A + (size_t)(b0 + r) * lda + acol0 + k0 + 4 * g);
      As[4*g+0][r] = v.x; As[4*g+1][r] = v.y; As[4*g+2][r] = v.z; As[4*g+3][r] = v.w;
    }
    {
      int kk = t >> 4, n4 = t & 15;
      float4 v = *reinterpret_cast<const float4*>(
          Bp + (size_t)(k0 + kk) * NS + nloc0 + 4 * n4);
      *reinterpret_cast<float4*>(&Bs[kk][4*n4]) = v;
    }
    __syncthreads();
#pragma unroll
    for (int k = 0; k < 16; ++k) {
      float4 a4 = *reinterpret_cast<const float4*>(&As[k][4*tb]);
      float4 b4 = *reinterpret_cast<const float4*>(&Bs[k][4*tn]);
      float av[4] = {a4.x, a4.y, a4.z, a4.w};
      float bv[4] = {b4.x, b4.y, b4.z, b4.w};
#pragma unroll
      for (int i = 0; i < 4; ++i)
#pragma unroll
        for (int j = 0; j < 4; ++j)
          acc[i][j] = fmaf(av[i], bv[j], acc[i][j]);
    }
    __syncthreads();
  }
#pragma unroll
  for (int i = 0; i < 4; ++i) {
    int row = b0 + 4*tb + i;
    int col = n0 + 4*tn;
    float4 o;
    o.x = acc[i][0] + bias[col + 0];
    o.y = acc[i][1] + bias[col + 1];
    o.z = acc[i][2] + bias[col + 2];
    o.w = acc[i][3] + bias[col + 3];
    *reinterpret_cast<float4*>(C + (size_t)row * ldc + col) = o;
  }
}

// ---------------- K3a: p = exp(masked score) + group sums (no-max) ----------------
// Round-5 structure: block 16b x 16u, m chunks of 8; thread u=t&15, tb, tm;
// micro 4b x 2m at fixed u; each (tm,j) owns group g=2tm+j completely.
__global__ __launch_bounds__(256) void scores_psum_kernel(
    const float* __restrict__ att,   // [512][512][32]
    const float* __restrict__ ma,    // [512][512][32]
    const float* __restrict__ rnd,   // [512][512][512]
    const float* __restrict__ temp,  // [512]
    float* __restrict__ wout,        // [512][512][512] <- p values
    float* __restrict__ stats)       // outs region base
{
  __shared__ float At[16 * 516];
  __shared__ float Ma[16 * 260];
  const int b0 = blockIdx.x * 16;
  const int u0 = blockIdx.y * 16;
  const int t  = threadIdx.x;
  const int u  = t & 15, tb = (t >> 4) & 3, tm = t >> 6;

  {  // stage att tile once
    int r = t >> 4, base = t & 15;
    const float* src = att + (size_t)(b0 + r) * 16384 + u0 * 32;
#pragma unroll
    for (int g = 0; g < 8; ++g) {
      int i4 = base + 16 * g;
      int uu = i4 >> 3, d4 = i4 & 7;
      float4 v = *reinterpret_cast<const float4*>(src + 4 * i4);
      *reinterpret_cast<float4*>(&At[uu*516 + d4*64 + (r ^ ((2*d4) & 15))*4]) = v;
    }
  }
  const float tmp = temp[u0 + u];
  float Ls[4][2];
#pragma unroll
  for (int i = 0; i < 4; ++i)
#pragma unroll
    for (int j = 0; j < 2; ++j) Ls[i][j] = 0.f;

  for (int m0 = 0; m0 < 512; m0 += 8) {
    float rv[4][2];
#pragma unroll
    for (int i = 0; i < 4; ++i)
#pragma unroll
      for (int j = 0; j < 2; ++j)
        rv[i][j] = rnd[((size_t)(b0 + 4*tb + i) * 512 + m0 + 2*tm + j) * 512 + u0 + u];
    __syncthreads();
    {  // stage 8 ma rows
      int r = t >> 5, base = t & 31;
      const float* src = ma + (size_t)(m0 + r) * 16384 + u0 * 32;
#pragma unroll
      for (int g = 0; g < 4; ++g) {
        int i4 = base + 32 * g;
        int uu = i4 >> 3, d4 = i4 & 7;
        float4 v = *reinterpret_cast<const float4*>(src + 4 * i4);
        *reinterpret_cast<float4*>(&Ma[uu*260 + d4*32 + ((r ^ d4) & 7)*4]) = v;
      }
    }
    __syncthreads();
    float acc[4][2] = {};
#pragma unroll
    for (int d4 = 0; d4 < 8; ++d4) {
      const int sw = (2*d4) & 15;
      float4 av[4], mv[2];
#pragma unroll
      for (int i = 0; i < 4; ++i)
        av[i] = *reinterpret_cast<const float4*>(&At[u*516 + d4*64 + ((4*tb+i) ^ sw)*4]);
#pragma unroll
      for (int j = 0; j < 2; ++j)
        mv[j] = *reinterpret_cast<const float4*>(&Ma[u*260 + d4*32 + (((2*tm+j) ^ d4) & 7)*4]);
#pragma unroll
      for (int i = 0; i < 4; ++i)
#pragma unroll
        for (int j = 0; j < 2; ++j) {
          acc[i][j] = fmaf(av[i].x, mv[j].x, acc[i][j]);
          acc[i][j] = fmaf(av[i].y, mv[j].y, acc[i][j]);
          acc[i][j] = fmaf(av[i].z, mv[j].z, acc[i][j]);
          acc[i][j] = fmaf(av[i].w, mv[j].w, acc[i][j]);
        }
    }
#pragma unroll
    for (int i = 0; i < 4; ++i)
#pragma unroll
      for (int j = 0; j < 2; ++j) {
        int gb = b0 + 4*tb + i, gm = m0 + 2*tm + j;
        float p;
        if ((rv[i][j] < 0.1f) | (gm == gb)) p = 0.f;
        else                                p = __expf(acc[i][j] * tmp);
        wout[((size_t)gb * 512 + gm) * 512 + u0 + u] = p;
        Ls[i][j] += p;
      }
  }
#pragma unroll
  for (int i = 0; i < 4; ++i)
#pragma unroll
    for (int j = 0; j < 2; ++j) {
      int b = b0 + 4*tb + i, g = 2*tm + j;
      stats[((size_t)b * 512 + u0 + u) * 32 + g] = 1.0f / (8.0f * Ls[i][j]);
    }
}

// ---------------- K3b v3: w = p*IL + outputs, 16b x 16u blocks ----------------
// Identical structure to round-5 emit_v2, minus the exp (p pre-exponentiated).
__global__ __launch_bounds__(256) void emit_outputs_v3(
    const float* __restrict__ mo,    // [512][512][32]
    float* __restrict__ w,           // in: p values, out: final w
    float* __restrict__ outs)        // in: stats cells (IL), out: outputs
{
  __shared__ float MoL[8 * 16 * 32];
  __shared__ float E[8 * 16 * 17];
  const int u0 = blockIdx.x * 16;
  const int b0 = blockIdx.y * 16;
  const int t  = threadIdx.x;
  const int ab = t >> 4, am = (t >> 1) & 7, uh = t & 1;
  const int pu = t >> 4, bq = (t >> 2) & 3, dh = t & 3;

  // IL for (b=ab, u=u0+uh*8+j, g=am)
  float Sreg[8];
  {
    const float* cb = outs + ((size_t)(b0 + ab) * 512 + u0 + uh * 8) * 32;
#pragma unroll
    for (int j = 0; j < 8; ++j) Sreg[j] = cb[j * 32 + am];
  }

  float4 acc[4][2];
#pragma unroll
  for (int i = 0; i < 4; ++i) {
    acc[i][0] = make_float4(0.f, 0.f, 0.f, 0.f);
    acc[i][1] = make_float4(0.f, 0.f, 0.f, 0.f);
  }

  float* wbase = w + (size_t)(b0 + ab) * 262144 + u0 + uh * 8;   // + m*512

  const float* msrc0;  const float* msrc1;  const float* msrc2;  const float* msrc3;
  int loff0, loff1, loff2, loff3;
  {
    int P, mm, uu, dq;
    P = t;          mm = P >> 7; uu = (P >> 3) & 15; dq = P & 7;
    msrc0 = mo + (size_t)mm * 16384 + (size_t)(u0 + uu) * 32 + (dq ^ (uu & 7)) * 4;
    loff0 = P * 4;
    P = 256 + t;    mm = P >> 7; uu = (P >> 3) & 15; dq = P & 7;
    msrc1 = mo + (size_t)mm * 16384 + (size_t)(u0 + uu) * 32 + (dq ^ (uu & 7)) * 4;
    loff1 = P * 4;
    P = 512 + t;    mm = P >> 7; uu = (P >> 3) & 15; dq = P & 7;
    msrc2 = mo + (size_t)mm * 16384 + (size_t)(u0 + uu) * 32 + (dq ^ (uu & 7)) * 4;
    loff2 = P * 4;
    P = 768 + t;    mm = P >> 7; uu = (P >> 3) & 15; dq = P & 7;
    msrc3 = mo + (size_t)mm * 16384 + (size_t)(u0 + uu) * 32 + (dq ^ (uu & 7)) * 4;
    loff3 = P * 4;
  }

  float4 wpre0, wpre1, smo0, smo1, smo2, smo3;
  {
    const float* wp = wbase + (size_t)am * 512;
    wpre0 = *reinterpret_cast<const float4*>(wp);
    wpre1 = *reinterpret_cast<const float4*>(wp + 4);
    smo0 = *reinterpret_cast<const float4*>(msrc0);
    smo1 = *reinterpret_cast<const float4*>(msrc1);
    smo2 = *reinterpret_cast<const float4*>(msrc2);
    smo3 = *reinterpret_cast<const float4*>(msrc3);
  }

#pragma unroll 1
  for (int c = 0; c < 64; ++c) {
    const int mc = c * 8;
    if (c) __syncthreads();            // phase B of c-1 done with E/MoL

    // ---- phase A: v = p*IL, write w + E; ds_write staged mo ----
    {
      float* wp = wbase + (size_t)(mc + am) * 512;
      float s0[4] = {wpre0.x, wpre0.y, wpre0.z, wpre0.w};
      float s1[4] = {wpre1.x, wpre1.y, wpre1.z, wpre1.w};
#pragma unroll
      for (int e2 = 0; e2 < 4; ++e2) {
        float v = s0[e2] * Sreg[e2];
        s0[e2] = v;
        E[(am * 16 + uh * 8 + e2) * 17 + ab] = v;
      }
#pragma unroll
      for (int e2 = 0; e2 < 4; ++e2) {
        float v = s1[e2] * Sreg[4 + e2];
        s1[e2] = v;
        E[(am * 16 + uh * 8 + 4 + e2) * 17 + ab] = v;
      }
      *reinterpret_cast<float4*>(wp)     = make_float4(s0[0], s0[1], s0[2], s0[3]);
      *reinterpret_cast<float4*>(wp + 4) = make_float4(s1[0], s1[1], s1[2], s1[3]);
    }
    *reinterpret_cast<float4*>(&MoL[loff0]) = smo0;
    *reinterpret_cast<float4*>(&MoL[loff1]) = smo1;
    *reinterpret_cast<float4*>(&MoL[loff2]) = smo2;
    *reinterpret_cast<float4*>(&MoL[loff3]) = smo3;
    __syncthreads();                   // E + MoL ready

    // ---- issue prefetch for chunk c+1 ----
    if (c < 63) {
      const float* wp = wbase + (size_t)(mc + 8 + am) * 512;
      wpre0 = *reinterpret_cast<const float4*>(wp);
      wpre1 = *reinterpret_cast<const float4*>(wp + 4);
      const size_t moff = (size_t)(mc + 8) * 16384;
      smo0 = *reinterpret_cast<const float4*>(msrc0 + moff);
      smo1 = *reinterpret_cast<const float4*>(msrc1 + moff);
      smo2 = *reinterpret_cast<const float4*>(msrc2 + moff);
      smo3 = *reinterpret_cast<const float4*>(msrc3 + moff);
    }

    // ---- phase B: acc[4b][8d] += E[m][pu][4b] * Mo[m][pu][8d] ----
#pragma unroll
    for (int m = 0; m < 8; ++m) {
      float4 ef = *reinterpret_cast<const float4*>(&E[(m * 16 + pu) * 17 + 4 * bq]);
      float4 v0 = *reinterpret_cast<const float4*>(
          &MoL[(m * 16 + pu) * 32 + (((2 * dh) ^ (pu & 7)) * 4)]);
      float4 v1 = *reinterpret_cast<const float4*>(
          &MoL[(m * 16 + pu) * 32 + (((2 * dh + 1) ^ (pu & 7)) * 4)]);
      float es[4] = {ef.x, ef.y, ef.z, ef.w};
#pragma unroll
      for (int i = 0; i < 4; ++i) {
        acc[i][0].x = fmaf(es[i], v0.x, acc[i][0].x);
        acc[i][0].y = fmaf(es[i], v0.y, acc[i][0].y);
        acc[i][0].z = fmaf(es[i], v0.z, acc[i][0].z);
        acc[i][0].w = fmaf(es[i], v0.w, acc[i][0].w);
        acc[i][1].x = fmaf(es[i], v1.x, acc[i][1].x);
        acc[i][1].y = fmaf(es[i], v1.y, acc[i][1].y);
        acc[i][1].z = fmaf(es[i], v1.z, acc[i][1].z);
        acc[i][1].w = fmaf(es[i], v1.w, acc[i][1].w);
      }
    }
  }

  // epilogue: overwrite stats cells with final outputs
#pragma unroll
  for (int i = 0; i < 4; ++i) {
    float* dst = outs + ((size_t)(b0 + 4 * bq + i) * 512 + u0 + pu) * 32 + 8 * dh;
    *reinterpret_cast<float4*>(dst)     = acc[i][0];
    *reinterpret_cast<float4*>(dst + 4) = acc[i][1];
  }
}

extern "C" void kernel_launch(void* const* d_in, const int* in_sizes, int n_in,
                              void* d_out, int out_size, void* d_ws, size_t ws_size,
                              hipStream_t stream) {
  const float* x    = (const float*)d_in[0];   // [512][4096]
  const float* ma   = (const float*)d_in[1];   // [512][512][32]
  const float* mo   = (const float*)d_in[2];   // [512][512][32]
  const float* rnd  = (const float*)d_in[3];   // [512][512][512]
  const float* w1   = (const float*)d_in[4];   // [8][512][256]
  const float* b1   = (const float*)d_in[5];   // [8][256]
  const float* w2   = (const float*)d_in[6];   // [8][256][2048]
  const float* b2   = (const float*)d_in[7];   // [8][2048]
  const float* temp = (const float*)d_in[8];   // [512]

  float* out  = (float*)d_out;
  float* att  = out;                  // 8388608
  float* ga   = out + 8388608;        // 1048576
  float* wbuf = out + 9437184;        // 134217728
  float* outs = out + 143654912;      // 8388608

  gemm_split<<<dim3(32, 8), 256, 0, stream>>>(x, 4096, 512, w1, 256, b1, ga, 2048);
  gemm_split<<<dim3(256, 8), 256, 0, stream>>>(ga, 2048, 256, w2, 2048, b2, att, 16384);
  scores_psum_kernel<<<dim3(32, 32), 256, 0, stream>>>(att, ma, rnd, temp, wbuf, outs);
  emit_outputs_v3<<<dim3(32, 32), 256, 0, stream>>>(mo, wbuf, outs);
}

// Round 8
// 843.232 us; speedup vs baseline: 1.0936x; 1.0675x over previous
//
#include <hip/hip_runtime.h>
#include <math.h>

#define NEGBIG (-1e30f)
#define GLB_PTR(x) ((const __attribute__((address_space(1))) void*)(x))
#define LDS_PTR(x) ((__attribute__((address_space(3))) void*)(x))

// Sizes: B=512, S=8, U=512, D=32, G=8, DIM_IN=4096, DAG=2048
// out layout: att[512*16384] | ga[512*2048] | w[512^3] | outputs[512*16384]
// No-max softmax: pass 1 stores p = exp(s) (masked -> 0) into the w region and
// accumulates L_g = sum p; stats cell (b,u) floats [0..7] = 1/(8 L_g).
// Pass 2: w = p * IL_g + PV accumulation. Stats cells are overwritten by outputs.

// ---------------- K1/K2: per-split fp32 GEMM (64x64 tile, Kstep 16) ----------------
__global__ __launch_bounds__(256) void gemm_split(
    const float* __restrict__ A, int lda, int Ksz,
    const float* __restrict__ Bw, int NS,
    const float* __restrict__ bias,
    float* __restrict__ C, int ldc)
{
  const int n0 = blockIdx.x * 64;
  const int b0 = blockIdx.y * 64;
  const int s  = n0 / NS;
  const float* Bp = Bw + (size_t)s * Ksz * NS;
  const int nloc0 = n0 - s * NS;
  const int acol0 = s * Ksz;

  __shared__ float As[16][64];
  __shared__ float Bs[16][64];

  const int t  = threadIdx.x;
  const int tb = t & 15, tn = t >> 4;
  float acc[4][4] = {};

  for (int k0 = 0; k0 < Ksz; k0 += 16) {
    {
      int r = t & 63, g = t >> 6;
      float4 v = *reinterpret_cast<const float4*>(
          A + (size_t)(b0 + r) * lda + acol0 + k0 + 4 * g);
      As[4*g+0][r] = v.x; As[4*g+1][r] = v.y; As[4*g+2][r] = v.z; As[4*g+3][r] = v.w;
    }
    {
      int kk = t >> 4, n4 = t & 15;
      float4 v = *reinterpret_cast<const float4*>(
          Bp + (size_t)(k0 + kk) * NS + nloc0 + 4 * n4);
      *reinterpret_cast<float4*>(&Bs[kk][4*n4]) = v;
    }
    __syncthreads();
#pragma unroll
    for (int k = 0; k < 16; ++k) {
      float4 a4 = *reinterpret_cast<const float4*>(&As[k][4*tb]);
      float4 b4 = *reinterpret_cast<const float4*>(&Bs[k][4*tn]);
      float av[4] = {a4.x, a4.y, a4.z, a4.w};
      float bv[4] = {b4.x, b4.y, b4.z, b4.w};
#pragma unroll
      for (int i = 0; i < 4; ++i)
#pragma unroll
        for (int j = 0; j < 4; ++j)
          acc[i][j] = fmaf(av[i], bv[j], acc[i][j]);
    }
    __syncthreads();
  }
#pragma unroll
  for (int i = 0; i < 4; ++i) {
    int row = b0 + 4*tb + i;
    int col = n0 + 4*tn;
    float4 o;
    o.x = acc[i][0] + bias[col + 0];
    o.y = acc[i][1] + bias[col + 1];
    o.z = acc[i][2] + bias[col + 2];
    o.w = acc[i][3] + bias[col + 3];
    *reinterpret_cast<float4*>(C + (size_t)row * ldc + col) = o;
  }
}

// ---------------- K3a v3: p = exp(masked score) + group sums ----------------
// Block 16b x 16u; m-chunks of 16. Thread (u=t&15, tbb=(t>>4)&7, tm=t>>7):
// micro 2b x 8m at fixed u; att rows in 64 VGPRs (no At LDS at all).
// ma staged via global_load_lds into linear LDS f4-slots  s = m*128 + u*8 + dqS,
// holding d-quad  dq = dqS ^ (u&7)  (source-side swizzle == read-side swizzle).
// Reads per (m,d4): 16 u-addresses x 4-way broadcast, <=2-way conflicts.
// Group identity: m = m0 + 8*tm + j  =>  g = m & 7 = j (thread-static).
__global__ __launch_bounds__(256) void scores_psum_v3(
    const float* __restrict__ att,   // [512][512][32]
    const float* __restrict__ ma,    // [512][512][32]
    const float* __restrict__ rnd,   // [512][512][512]
    const float* __restrict__ temp,  // [512]
    float* __restrict__ wout,        // [512][512][512] <- p values
    float* __restrict__ stats)       // outs region base
{
  __shared__ float MaL[16 * 16 * 32];    // 32 KB, f4-slot layout above
  const int b0 = blockIdx.x * 16;
  const int u0 = blockIdx.y * 16;
  const int t  = threadIdx.x;
  const int u = t & 15, tbb = (t >> 4) & 7, tm = t >> 7;
  const int w = t >> 6, l = t & 63;

  // att rows in registers (the block's whole A-tile, distributed)
  float4 A[2][8];
#pragma unroll
  for (int i = 0; i < 2; ++i) {
    const float* ap = att + (size_t)(b0 + 2 * tbb + i) * 16384
                    + (size_t)(u0 + u) * 32;
#pragma unroll
    for (int k = 0; k < 8; ++k)
      A[i][k] = *reinterpret_cast<const float4*>(ap + 4 * k);
  }
  const float tmp = temp[u0 + u];

  // per-lane global source offsets for the wave's 8 global_load_lds
  int offK[8];
#pragma unroll
  for (int k = 0; k < 8; ++k) {
    int slot = (w * 8 + k) * 64 + l;          // linear f4 slot this lane fills
    int mm = slot >> 7, uu = (slot >> 3) & 15, dqS = slot & 7;
    offK[k] = mm * 16384 + (u0 + uu) * 32 + ((dqS ^ (uu & 7)) << 2);
  }

  // rnd/wout row bases for the 2 owned b-rows
  const float* rrow0 = rnd + (size_t)(b0 + 2 * tbb) * 262144 + u0 + u;
  const float* rrow1 = rrow0 + 262144;
  float* wrow0 = wout + (size_t)(b0 + 2 * tbb) * 262144 + u0 + u;
  float* wrow1 = wrow0 + 262144;

  float Ls[2][8];
#pragma unroll
  for (int i = 0; i < 2; ++i)
#pragma unroll
    for (int j = 0; j < 8; ++j) Ls[i][j] = 0.f;

  // prologue: stage chunk 0 + rnd chunk 0
#pragma unroll
  for (int k = 0; k < 8; ++k)
    __builtin_amdgcn_global_load_lds(GLB_PTR(ma + (size_t)offK[k]),
                                     LDS_PTR(&MaL[(w * 8 + k) * 256]), 16, 0, 0);
  float rc[2][8], rn[2][8];
#pragma unroll
  for (int j = 0; j < 8; ++j) {
    rc[0][j] = rrow0[(size_t)(8 * tm + j) * 512];
    rc[1][j] = rrow1[(size_t)(8 * tm + j) * 512];
  }

#pragma unroll 1
  for (int c = 0; c < 32; ++c) {
    const int m0 = c * 16;
    __syncthreads();                  // drains gloads + prefetches: MaL[c], rn ready

    if (c < 31) {                     // issue next chunk's rnd early
#pragma unroll
      for (int j = 0; j < 8; ++j) {
        rn[0][j] = rrow0[(size_t)(m0 + 16 + 8 * tm + j) * 512];
        rn[1][j] = rrow1[(size_t)(m0 + 16 + 8 * tm + j) * 512];
      }
    }

    // ---- compute: acc[2b][8m] over d ----
    float acc[2][8] = {};
#pragma unroll
    for (int d4 = 0; d4 < 8; ++d4) {
      const int dsw = d4 ^ (u & 7);
      const float4 a0 = A[0][d4], a1 = A[1][d4];
#pragma unroll
      for (int j = 0; j < 8; ++j) {
        float4 mv = *reinterpret_cast<const float4*>(
            &MaL[(((8 * tm + j) * 128) + u * 8 + dsw) * 4]);
        acc[0][j] = fmaf(a0.x, mv.x, acc[0][j]);
        acc[0][j] = fmaf(a0.y, mv.y, acc[0][j]);
        acc[0][j] = fmaf(a0.z, mv.z, acc[0][j]);
        acc[0][j] = fmaf(a0.w, mv.w, acc[0][j]);
        acc[1][j] = fmaf(a1.x, mv.x, acc[1][j]);
        acc[1][j] = fmaf(a1.y, mv.y, acc[1][j]);
        acc[1][j] = fmaf(a1.z, mv.z, acc[1][j]);
        acc[1][j] = fmaf(a1.w, mv.w, acc[1][j]);
      }
    }

    // ---- emit p + accumulate group sums ----
#pragma unroll
    for (int j = 0; j < 8; ++j) {
      const int gm = m0 + 8 * tm + j;
      {
        const int gb = b0 + 2 * tbb;
        float p = ((rc[0][j] < 0.1f) | (gm == gb)) ? 0.f
                                                   : __expf(acc[0][j] * tmp);
        wrow0[(size_t)gm * 512] = p;
        Ls[0][j] += p;
      }
      {
        const int gb = b0 + 2 * tbb + 1;
        float p = ((rc[1][j] < 0.1f) | (gm == gb)) ? 0.f
                                                   : __expf(acc[1][j] * tmp);
        wrow1[(size_t)gm * 512] = p;
        Ls[1][j] += p;
      }
    }

    __syncthreads();                  // block done reading MaL[c]
    if (c < 31) {
#pragma unroll
      for (int k = 0; k < 8; ++k)
        __builtin_amdgcn_global_load_lds(
            GLB_PTR(ma + (size_t)offK[k] + (size_t)(m0 + 16) * 16384),
            LDS_PTR(&MaL[(w * 8 + k) * 256]), 16, 0, 0);
#pragma unroll
      for (int j = 0; j < 8; ++j) { rc[0][j] = rn[0][j]; rc[1][j] = rn[1][j]; }
    }
  }

  // ---- merge tm-pair partial sums through LDS, write stats ----
  __syncthreads();
#pragma unroll
  for (int i = 0; i < 2; ++i)
#pragma unroll
    for (int j = 0; j < 8; ++j)
      MaL[t * 16 + i * 8 + j] = Ls[i][j];
  __syncthreads();
  if (tm == 0) {
#pragma unroll
    for (int i = 0; i < 2; ++i)
#pragma unroll
      for (int j = 0; j < 8; ++j) {
        float tot = Ls[i][j] + MaL[(t + 128) * 16 + i * 8 + j];
        stats[((size_t)(b0 + 2 * tbb + i) * 512 + u0 + u) * 32 + j] =
            1.0f / (8.0f * tot);
      }
  }
}

// ---------------- K3b v3: w = p*IL + outputs, 16b x 16u blocks ----------------
__global__ __launch_bounds__(256) void emit_outputs_v3(
    const float* __restrict__ mo,    // [512][512][32]
    float* __restrict__ w,           // in: p values, out: final w
    float* __restrict__ outs)        // in: stats cells (IL), out: outputs
{
  __shared__ float MoL[8 * 16 * 32];
  __shared__ float E[8 * 16 * 17];
  const int u0 = blockIdx.x * 16;
  const int b0 = blockIdx.y * 16;
  const int t  = threadIdx.x;
  const int ab = t >> 4, am = (t >> 1) & 7, uh = t & 1;
  const int pu = t >> 4, bq = (t >> 2) & 3, dh = t & 3;

  float Sreg[8];
  {
    const float* cb = outs + ((size_t)(b0 + ab) * 512 + u0 + uh * 8) * 32;
#pragma unroll
    for (int j = 0; j < 8; ++j) Sreg[j] = cb[j * 32 + am];
  }

  float4 acc[4][2];
#pragma unroll
  for (int i = 0; i < 4; ++i) {
    acc[i][0] = make_float4(0.f, 0.f, 0.f, 0.f);
    acc[i][1] = make_float4(0.f, 0.f, 0.f, 0.f);
  }

  float* wbase = w + (size_t)(b0 + ab) * 262144 + u0 + uh * 8;   // + m*512

  const float* msrc0;  const float* msrc1;  const float* msrc2;  const float* msrc3;
  int loff0, loff1, loff2, loff3;
  {
    int P, mm, uu, dq;
    P = t;          mm = P >> 7; uu = (P >> 3) & 15; dq = P & 7;
    msrc0 = mo + (size_t)mm * 16384 + (size_t)(u0 + uu) * 32 + (dq ^ (uu & 7)) * 4;
    loff0 = P * 4;
    P = 256 + t;    mm = P >> 7; uu = (P >> 3) & 15; dq = P & 7;
    msrc1 = mo + (size_t)mm * 16384 + (size_t)(u0 + uu) * 32 + (dq ^ (uu & 7)) * 4;
    loff1 = P * 4;
    P = 512 + t;    mm = P >> 7; uu = (P >> 3) & 15; dq = P & 7;
    msrc2 = mo + (size_t)mm * 16384 + (size_t)(u0 + uu) * 32 + (dq ^ (uu & 7)) * 4;
    loff2 = P * 4;
    P = 768 + t;    mm = P >> 7; uu = (P >> 3) & 15; dq = P & 7;
    msrc3 = mo + (size_t)mm * 16384 + (size_t)(u0 + uu) * 32 + (dq ^ (uu & 7)) * 4;
    loff3 = P * 4;
  }

  float4 wpre0, wpre1, smo0, smo1, smo2, smo3;
  {
    const float* wp = wbase + (size_t)am * 512;
    wpre0 = *reinterpret_cast<const float4*>(wp);
    wpre1 = *reinterpret_cast<const float4*>(wp + 4);
    smo0 = *reinterpret_cast<const float4*>(msrc0);
    smo1 = *reinterpret_cast<const float4*>(msrc1);
    smo2 = *reinterpret_cast<const float4*>(msrc2);
    smo3 = *reinterpret_cast<const float4*>(msrc3);
  }

#pragma unroll 1
  for (int c = 0; c < 64; ++c) {
    const int mc = c * 8;
    if (c) __syncthreads();            // phase B of c-1 done with E/MoL

    // ---- phase A: v = p*IL, write w + E; ds_write staged mo ----
    {
      float* wp = wbase + (size_t)(mc + am) * 512;
      float s0[4] = {wpre0.x, wpre0.y, wpre0.z, wpre0.w};
      float s1[4] = {wpre1.x, wpre1.y, wpre1.z, wpre1.w};
#pragma unroll
      for (int e2 = 0; e2 < 4; ++e2) {
        float v = s0[e2] * Sreg[e2];
        s0[e2] = v;
        E[(am * 16 + uh * 8 + e2) * 17 + ab] = v;
      }
#pragma unroll
      for (int e2 = 0; e2 < 4; ++e2) {
        float v = s1[e2] * Sreg[4 + e2];
        s1[e2] = v;
        E[(am * 16 + uh * 8 + 4 + e2) * 17 + ab] = v;
      }
      *reinterpret_cast<float4*>(wp)     = make_float4(s0[0], s0[1], s0[2], s0[3]);
      *reinterpret_cast<float4*>(wp + 4) = make_float4(s1[0], s1[1], s1[2], s1[3]);
    }
    *reinterpret_cast<float4*>(&MoL[loff0]) = smo0;
    *reinterpret_cast<float4*>(&MoL[loff1]) = smo1;
    *reinterpret_cast<float4*>(&MoL[loff2]) = smo2;
    *reinterpret_cast<float4*>(&MoL[loff3]) = smo3;
    __syncthreads();                   // E + MoL ready

    // ---- issue prefetch for chunk c+1 ----
    if (c < 63) {
      const float* wp = wbase + (size_t)(mc + 8 + am) * 512;
      wpre0 = *reinterpret_cast<const float4*>(wp);
      wpre1 = *reinterpret_cast<const float4*>(wp + 4);
      const size_t moff = (size_t)(mc + 8) * 16384;
      smo0 = *reinterpret_cast<const float4*>(msrc0 + moff);
      smo1 = *reinterpret_cast<const float4*>(msrc1 + moff);
      smo2 = *reinterpret_cast<const float4*>(msrc2 + moff);
      smo3 = *reinterpret_cast<const float4*>(msrc3 + moff);
    }

    // ---- phase B: acc[4b][8d] += E[m][pu][4b] * Mo[m][pu][8d] ----
#pragma unroll
    for (int m = 0; m < 8; ++m) {
      float4 ef = *reinterpret_cast<const float4*>(&E[(m * 16 + pu) * 17 + 4 * bq]);
      float4 v0 = *reinterpret_cast<const float4*>(
          &MoL[(m * 16 + pu) * 32 + (((2 * dh) ^ (pu & 7)) * 4)]);
      float4 v1 = *reinterpret_cast<const float4*>(
          &MoL[(m * 16 + pu) * 32 + (((2 * dh + 1) ^ (pu & 7)) * 4)]);
      float es[4] = {ef.x, ef.y, ef.z, ef.w};
#pragma unroll
      for (int i = 0; i < 4; ++i) {
        acc[i][0].x = fmaf(es[i], v0.x, acc[i][0].x);
        acc[i][0].y = fmaf(es[i], v0.y, acc[i][0].y);
        acc[i][0].z = fmaf(es[i], v0.z, acc[i][0].z);
        acc[i][0].w = fmaf(es[i], v0.w, acc[i][0].w);
        acc[i][1].x = fmaf(es[i], v1.x, acc[i][1].x);
        acc[i][1].y = fmaf(es[i], v1.y, acc[i][1].y);
        acc[i][1].z = fmaf(es[i], v1.z, acc[i][1].z);
        acc[i][1].w = fmaf(es[i], v1.w, acc[i][1].w);
      }
    }
  }

  // epilogue: overwrite stats cells with final outputs
#pragma unroll
  for (int i = 0; i < 4; ++i) {
    float* dst = outs + ((size_t)(b0 + 4 * bq + i) * 512 + u0 + pu) * 32 + 8 * dh;
    *reinterpret_cast<float4*>(dst)     = acc[i][0];
    *reinterpret_cast<float4*>(dst + 4) = acc[i][1];
  }
}

extern "C" void kernel_launch(void* const* d_in, const int* in_sizes, int n_in,
                              void* d_out, int out_size, void* d_ws, size_t ws_size,
                              hipStream_t stream) {
  const float* x    = (const float*)d_in[0];   // [512][4096]
  const float* ma   = (const float*)d_in[1];   // [512][512][32]
  const float* mo   = (const float*)d_in[2];   // [512][512][32]
  const float* rnd  = (const float*)d_in[3];   // [512][512][512]
  const float* w1   = (const float*)d_in[4];   // [8][512][256]
  const float* b1   = (const float*)d_in[5];   // [8][256]
  const float* w2   = (const float*)d_in[6];   // [8][256][2048]
  const float* b2   = (const float*)d_in[7];   // [8][2048]
  const float* temp = (const float*)d_in[8];   // [512]

  float* out  = (float*)d_out;
  float* att  = out;                  // 8388608
  float* ga   = out + 8388608;        // 1048576
  float* wbuf = out + 9437184;        // 134217728
  float* outs = out + 143654912;      // 8388608

  gemm_split<<<dim3(32, 8), 256, 0, stream>>>(x, 4096, 512, w1, 256, b1, ga, 2048);
  gemm_split<<<dim3(256, 8), 256, 0, stream>>>(ga, 2048, 256, w2, 2048, b2, att, 16384);
  scores_psum_v3<<<dim3(32, 32), 256, 0, stream>>>(att, ma, rnd, temp, wbuf, outs);
  emit_outputs_v3<<<dim3(32, 32), 256, 0, stream>>>(mo, wbuf, outs);
}